// Round 1
// baseline (374.831 us; speedup 1.0000x reference)
//
#include <hip/hip_runtime.h>
#include <hip/hip_bf16.h>

typedef unsigned short u16;
typedef unsigned int u32;

typedef __bf16 bf16x8 __attribute__((ext_vector_type(8)));
typedef float f32x4 __attribute__((ext_vector_type(4)));

#define AS1 __attribute__((address_space(1)))
#define AS3 __attribute__((address_space(3)))

// fp32 -> bf16 round-to-nearest-even (bit trick; NaN irrelevant here)
__device__ __forceinline__ u16 f2bf(float f) {
    u32 u = __float_as_uint(f);
    u += 0x7fffu + ((u >> 16) & 1u);
    return (u16)(u >> 16);
}

// ---- conversion kernels (memory-bound, vectorized 16B loads/stores) ----

__global__ void cvt_x_kernel(const float4* __restrict__ x, uint4* __restrict__ y, int n8) {
    int stride = gridDim.x * blockDim.x;
    for (int i = blockIdx.x * blockDim.x + threadIdx.x; i < n8; i += stride) {
        float4 f0 = x[2 * i + 0];
        float4 f1 = x[2 * i + 1];
        union { u16 s[8]; uint4 v; } o;
        o.s[0] = f2bf(f0.x); o.s[1] = f2bf(f0.y); o.s[2] = f2bf(f0.z); o.s[3] = f2bf(f0.w);
        o.s[4] = f2bf(f1.x); o.s[5] = f2bf(f1.y); o.s[6] = f2bf(f1.z); o.s[7] = f2bf(f1.w);
        y[i] = o.v;
    }
}

// int4 codes (stored as int32, [-8,7]) -> bf16 (EXACT; scale applied in epilogue)
__global__ void cvt_w_kernel(const int4* __restrict__ q, uint4* __restrict__ y, int n8) {
    int stride = gridDim.x * blockDim.x;
    for (int i = blockIdx.x * blockDim.x + threadIdx.x; i < n8; i += stride) {
        int4 q0 = q[2 * i + 0];
        int4 q1 = q[2 * i + 1];
        union { u16 s[8]; uint4 v; } o;
        o.s[0] = f2bf((float)q0.x); o.s[1] = f2bf((float)q0.y);
        o.s[2] = f2bf((float)q0.z); o.s[3] = f2bf((float)q0.w);
        o.s[4] = f2bf((float)q1.x); o.s[5] = f2bf((float)q1.y);
        o.s[6] = f2bf((float)q1.z); o.s[7] = f2bf((float)q1.w);
        y[i] = o.v;
    }
}

// ---- GEMM: C[m][n] = scale[n] * sum_k A[m][k]*W[n][k] + bias[n] ----
// m97-structure: 128x128 tile, BK=32, 4 waves (2x2), 4x4 16x16x32-bf16 frags/wave,
// global_load_lds width-16 staging, LDS double-buffer, 1 barrier per K-step.

#define BM 128
#define BN 128
#define BK 32

__global__ __launch_bounds__(256, 2) void gemm_bf16_dq(
    const u16* __restrict__ A,      // [M][K] bf16
    const u16* __restrict__ W,      // [N][K] bf16
    const float* __restrict__ scale,
    const float* __restrict__ bias,
    float* __restrict__ C,
    int M, int N, int K)
{
    __shared__ u16 sA[2][BM * BK];  // 8192 B per buffer
    __shared__ u16 sB[2][BN * BK];

    const int nwg = gridDim.x;
    int bid = blockIdx.x;
    // XCD-aware swizzle (bijective when nwg % 8 == 0; here 2048)
    if ((nwg & 7) == 0) {
        int cpx = nwg >> 3;
        bid = (bid & 7) * cpx + (bid >> 3);
    }
    const int ntn = N / BN;
    const int tm = bid / ntn;
    const int tn = bid % ntn;

    const int t    = threadIdx.x;
    const int lane = t & 63;
    const int wave = t >> 6;
    const int wm   = wave >> 1;
    const int wn   = wave & 1;

    const size_t Kz = (size_t)K;
    // staging: thread t covers row (t>>2), k-bytes (t&3)*16 -> LDS linear byte t*16
    const u16* aSrc = A + (size_t)(tm * BM + (t >> 2)) * Kz + (size_t)((t & 3) * 8);
    const u16* bSrc = W + (size_t)(tn * BN + (t >> 2)) * Kz + (size_t)((t & 3) * 8);
    const size_t rowStep = 64 * Kz;     // issue 2 covers rows +64

    char* sAb = (char*)&sA[0][0];
    char* sBb = (char*)&sB[0][0];
    const int wbyte = wave * 1024;      // wave-uniform LDS base; HW adds lane*16

    f32x4 acc[4][4];
#pragma unroll
    for (int i = 0; i < 4; ++i)
#pragma unroll
        for (int j = 0; j < 4; ++j) acc[i][j] = (f32x4){0.f, 0.f, 0.f, 0.f};

    const int NK = K / BK;

    auto stage = [&](int buf, int kt) {
        const u16* a0 = aSrc + (size_t)kt * BK;
        const u16* b0 = bSrc + (size_t)kt * BK;
        const int base = buf * (BM * BK * 2);
        __builtin_amdgcn_global_load_lds((const AS1 void*)a0,
            (AS3 void*)(sAb + base + wbyte), 16, 0, 0);
        __builtin_amdgcn_global_load_lds((const AS1 void*)(a0 + rowStep),
            (AS3 void*)(sAb + base + 4096 + wbyte), 16, 0, 0);
        __builtin_amdgcn_global_load_lds((const AS1 void*)b0,
            (AS3 void*)(sBb + base + wbyte), 16, 0, 0);
        __builtin_amdgcn_global_load_lds((const AS1 void*)(b0 + rowStep),
            (AS3 void*)(sBb + base + 4096 + wbyte), 16, 0, 0);
    };

    stage(0, 0);
    __syncthreads();   // drains vmcnt(0) before barrier (compiler-emitted)

    // fragment offsets: A-frag lane l -> row (l&15), k = (l>>4)*8 .. +8 (16B contiguous)
    const int aoff = (wm * 64 + (lane & 15)) * BK + (lane >> 4) * 8;
    const int boff = (wn * 64 + (lane & 15)) * BK + (lane >> 4) * 8;

    for (int kt = 0; kt < NK; ++kt) {
        const int cur = kt & 1;
        if (kt + 1 < NK) stage(cur ^ 1, kt + 1);   // prefetch overlaps compute

        const u16* pa = &sA[cur][aoff];
        const u16* pb = &sB[cur][boff];
        bf16x8 af[4], bf[4];
#pragma unroll
        for (int i = 0; i < 4; ++i) af[i] = *(const bf16x8*)(pa + i * 16 * BK);
#pragma unroll
        for (int j = 0; j < 4; ++j) bf[j] = *(const bf16x8*)(pb + j * 16 * BK);
#pragma unroll
        for (int i = 0; i < 4; ++i)
#pragma unroll
            for (int j = 0; j < 4; ++j)
                acc[i][j] = __builtin_amdgcn_mfma_f32_16x16x32_bf16(af[i], bf[j], acc[i][j], 0, 0, 0);

        __syncthreads();   // one barrier per K-step: drains prefetch + guards reuse
    }

    // epilogue: C/D frag mapping (16x16x32): col = lane&15, row = (lane>>4)*4 + reg
    const int colb = tn * BN + wn * 64 + (lane & 15);
    const int rowb = tm * BM + wm * 64 + (lane >> 4) * 4;
#pragma unroll
    for (int j = 0; j < 4; ++j) {
        const int col = colb + j * 16;
        const float s = scale[col];
        const float b = bias[col];
#pragma unroll
        for (int i = 0; i < 4; ++i) {
            const int row = rowb + i * 16;
#pragma unroll
            for (int r = 0; r < 4; ++r)
                C[(size_t)(row + r) * N + col] = acc[i][j][r] * s + b;
        }
    }
}

extern "C" void kernel_launch(void* const* d_in, const int* in_sizes, int n_in,
                              void* d_out, int out_size, void* d_ws, size_t ws_size,
                              hipStream_t stream) {
    const float* x     = (const float*)d_in[0];
    const int*   qw    = (const int*)d_in[1];
    const float* scale = (const float*)d_in[2];
    const float* bias  = (const float*)d_in[3];
    float*       out   = (float*)d_out;

    const int N = in_sizes[2];            // DOUT = 4096
    const int K = in_sizes[1] / N;        // DIN  = 4096
    const int M = in_sizes[0] / K;        // B*S  = 8192

    // workspace: x_bf16 [M*K] then w_bf16 [N*K]  (needs (M+N)*K*2 = ~100.7 MB)
    u16* xb = (u16*)d_ws;
    u16* wb = xb + (size_t)M * K;

    cvt_x_kernel<<<2048, 256, 0, stream>>>((const float4*)x, (uint4*)xb, (M * K) / 8);
    cvt_w_kernel<<<2048, 256, 0, stream>>>((const int4*)qw, (uint4*)wb, (N * K) / 8);

    const int grid = (M / BM) * (N / BN); // 2048
    gemm_bf16_dq<<<grid, 256, 0, stream>>>(xb, wb, scale, bias, out, M, N, K);
}

// Round 2
// 294.044 us; speedup vs baseline: 1.2747x; 1.2747x over previous
//
#include <hip/hip_runtime.h>
#include <hip/hip_bf16.h>

typedef unsigned short u16;
typedef unsigned int u32;

typedef __bf16 bf16x8 __attribute__((ext_vector_type(8)));
typedef float f32x4 __attribute__((ext_vector_type(4)));

#define AS1 __attribute__((address_space(1)))
#define AS3 __attribute__((address_space(3)))

__device__ __forceinline__ u16 f2bf(float f) {
    u32 u = __float_as_uint(f);
    u += 0x7fffu + ((u >> 16) & 1u);
    return (u16)(u >> 16);
}

__global__ void cvt_x_kernel(const float4* __restrict__ x, uint4* __restrict__ y, int n8) {
    int stride = gridDim.x * blockDim.x;
    for (int i = blockIdx.x * blockDim.x + threadIdx.x; i < n8; i += stride) {
        float4 f0 = x[2 * i + 0];
        float4 f1 = x[2 * i + 1];
        union { u16 s[8]; uint4 v; } o;
        o.s[0] = f2bf(f0.x); o.s[1] = f2bf(f0.y); o.s[2] = f2bf(f0.z); o.s[3] = f2bf(f0.w);
        o.s[4] = f2bf(f1.x); o.s[5] = f2bf(f1.y); o.s[6] = f2bf(f1.z); o.s[7] = f2bf(f1.w);
        y[i] = o.v;
    }
}

__global__ void cvt_w_kernel(const int4* __restrict__ q, uint4* __restrict__ y, int n8) {
    int stride = gridDim.x * blockDim.x;
    for (int i = blockIdx.x * blockDim.x + threadIdx.x; i < n8; i += stride) {
        int4 q0 = q[2 * i + 0];
        int4 q1 = q[2 * i + 1];
        union { u16 s[8]; uint4 v; } o;
        o.s[0] = f2bf((float)q0.x); o.s[1] = f2bf((float)q0.y);
        o.s[2] = f2bf((float)q0.z); o.s[3] = f2bf((float)q0.w);
        o.s[4] = f2bf((float)q1.x); o.s[5] = f2bf((float)q1.y);
        o.s[6] = f2bf((float)q1.z); o.s[7] = f2bf((float)q1.w);
        y[i] = o.v;
    }
}

// ===== 256x256 8-phase GEMM (T2 swizzle + T3/T4 counted vmcnt + T5 setprio) =====
// C[m][n] = scale[n] * sum_k A[m][k]*W[n][k] + bias[n]
// BM=BN=256, BK=64, 512 thr (2Mx4N waves), LDS 128KiB dbuf, 16 MFMA/phase.

#define BM 256
#define BN 256
#define BK 64

// One phase: {ds-read subtile; stage pair; barrier; lgkm0; setprio1; 16 MFMA; setprio0; [vmcnt gate]; barrier}
template<int KS, int MLO, bool GATE, typename F>
__device__ __forceinline__ void phase(const char* aB, const char* bB,
    bf16x8 (&bfr)[2][4], f32x4 (&acc)[8][4], F&& stage)
{
    bf16x8 afr[4];
    if (MLO == 0) {
#pragma unroll
        for (int fn = 0; fn < 4; ++fn)
            bfr[KS][fn] = *(const bf16x8*)(bB + fn * 2048 + KS * 64);
    }
#pragma unroll
    for (int fm = 0; fm < 4; ++fm)
        afr[fm] = *(const bf16x8*)(aB + (MLO + fm) * 2048 + KS * 64);
    stage();
    __builtin_amdgcn_s_barrier();
    asm volatile("s_waitcnt lgkmcnt(0)" ::: "memory");
    __builtin_amdgcn_s_setprio(1);
#pragma unroll
    for (int fm = 0; fm < 4; ++fm)
#pragma unroll
        for (int fn = 0; fn < 4; ++fn)
            acc[MLO + fm][fn] = __builtin_amdgcn_mfma_f32_16x16x32_bf16(
                afr[fm], bfr[KS][fn], acc[MLO + fm][fn], 0, 0, 0);
    __builtin_amdgcn_s_setprio(0);
    if (GATE) asm volatile("s_waitcnt vmcnt(4)" ::: "memory");
    __builtin_amdgcn_s_barrier();
}

__global__ __launch_bounds__(512, 2) void gemm256(
    const u16* __restrict__ A,      // [M][K] bf16
    const u16* __restrict__ W,      // [N][K] bf16
    const float* __restrict__ scale,
    const float* __restrict__ bias,
    float* __restrict__ C,
    int M, int N, int K)
{
    __shared__ alignas(1024) char lds[131072];  // buf0: A@0 B@32768 ; buf1: A@65536 B@98304

    const int nwg = gridDim.x;
    int bid = blockIdx.x;
    if ((nwg & 7) == 0) { int cpx = nwg >> 3; bid = (bid & 7) * cpx + (bid >> 3); }
    const int ntn = N / BN;
    const int tm = bid / ntn, tn = bid % ntn;

    const int t = threadIdx.x;
    const int l = t & 63;
    const int w = t >> 6;
    const int wm = w >> 2, wn = w & 3;       // 2 x 4 wave grid; wave tile 128x64
    const size_t Kz = (size_t)K;

    // ---- staging: linear LDS dest (wave base + lane*16); PRE-SWIZZLED global source.
    // within-chunk slot s = t*16; swz flips byte-bit5 with bit9  =>  t' = t ^ ((t>>5&1)<<1)
    const int tp = t ^ (((t >> 5) & 1) << 1);
    const int sRow = tp >> 3;                // 0..63 within 64-row chunk
    const int sCol = (tp & 7) * 8;           // element col within 64-wide k-slice
    const u16* aSrc = A + (size_t)(tm * BM + sRow) * Kz + sCol;
    const u16* bSrc = W + (size_t)(tn * BN + sRow) * Kz + sCol;
    const int wByte = w * 1024;

    char* dA0 = lds + wByte;
    char* dB0 = lds + 32768 + wByte;
    char* dA1 = lds + 65536 + wByte;
    char* dB1 = lds + 98304 + wByte;

    // ---- reader bases, st_16x32 XOR-swizzle: bit9 of tile-linear = (l>>2)&1 (lane-only)
    const int xor5 = ((l >> 2) & 1) << 5;
    const int aOff = (((wm * 128 + (l & 15)) * 128) + ((l >> 4) * 16)) ^ xor5;
    const int bOff = (((wn * 64 + (l & 15)) * 128) + ((l >> 4) * 16)) ^ xor5;
    const char* aX = lds + aOff;
    const char* bX = lds + 32768 + bOff;
    const char* aY = lds + 65536 + aOff;
    const char* bY = lds + 98304 + bOff;

    f32x4 acc[8][4];
#pragma unroll
    for (int i = 0; i < 8; ++i)
#pragma unroll
        for (int j = 0; j < 4; ++j) acc[i][j] = (f32x4){0.f, 0.f, 0.f, 0.f};

    const int NT = K / BK;   // 64 K-tiles

    auto stagePair = [&](const u16* src, char* dst, int kt, int c0, int c1) {
        const u16* s0 = src + (size_t)c0 * 64 * Kz + (size_t)kt * 64;
        const u16* s1 = src + (size_t)c1 * 64 * Kz + (size_t)kt * 64;
        __builtin_amdgcn_global_load_lds((const AS1 void*)s0, (AS3 void*)(dst + c0 * 8192), 16, 0, 0);
        __builtin_amdgcn_global_load_lds((const AS1 void*)s1, (AS3 void*)(dst + c1 * 8192), 16, 0, 0);
    };

    // ---- prologue: tile0 full -> buf0; tile1 B -> buf1; counted gate
    stagePair(aSrc, dA0, 0, 0, 2);
    stagePair(bSrc, dB0, 0, 0, 1);
    stagePair(bSrc, dB0, 0, 2, 3);
    stagePair(aSrc, dA0, 0, 1, 3);
    stagePair(bSrc, dB1, 1, 0, 1);
    stagePair(bSrc, dB1, 1, 2, 3);
    asm volatile("s_waitcnt vmcnt(4)" ::: "memory");
    __builtin_amdgcn_s_barrier();

    bf16x8 bfr[2][4];

    // ---- main loop: 2 K-tiles per iteration, 8 phases.
    // Stage schedule (derived so vmcnt(4)@P4,P8 provably covers every consumed chunk):
    //  P1:(2i+1).A02->buf1  P2:(2i+1).A13->buf1  P3:e.A02->buf0  P4:e.B01->buf0 +gate
    //  P5:e.B23->buf0       P6:e.A13->buf0       P7:o.B01->buf1  P8:o.B23->buf1 +gate
#pragma unroll 1
    for (int i = 0; i < NT / 2; ++i) {
        const int yt = 2 * i + 1;
        const int e  = (2 * i + 2) & (NT - 1);   // wraps harmlessly on last iter
        const int o  = (2 * i + 3) & (NT - 1);
        phase<0, 0, false>(aX, bX, bfr, acc, [&] { stagePair(aSrc, dA1, yt, 0, 2); });
        phase<1, 0, false>(aX, bX, bfr, acc, [&] { stagePair(aSrc, dA1, yt, 1, 3); });
        phase<0, 4, false>(aX, bX, bfr, acc, [&] { stagePair(aSrc, dA0, e, 0, 2); });
        phase<1, 4, true >(aX, bX, bfr, acc, [&] { stagePair(bSrc, dB0, e, 0, 1); });
        phase<0, 0, false>(aY, bY, bfr, acc, [&] { stagePair(bSrc, dB0, e, 2, 3); });
        phase<1, 0, false>(aY, bY, bfr, acc, [&] { stagePair(aSrc, dA0, e, 1, 3); });
        phase<0, 4, false>(aY, bY, bfr, acc, [&] { stagePair(bSrc, dB1, o, 0, 1); });
        phase<1, 4, true >(aY, bY, bfr, acc, [&] { stagePair(bSrc, dB1, o, 2, 3); });
    }

    // ---- epilogue: C/D frag (16x16x32): col = lane&15, row = (lane>>4)*4 + reg
    const int colb = tn * BN + wn * 64 + (l & 15);
    const int rowb = tm * BM + wm * 128 + (l >> 4) * 4;
#pragma unroll
    for (int fn = 0; fn < 4; ++fn) {
        const int col = colb + fn * 16;
        const float s = scale[col];
        const float b = bias[col];
#pragma unroll
        for (int fm = 0; fm < 8; ++fm) {
            const int row = rowb + fm * 16;
#pragma unroll
            for (int r = 0; r < 4; ++r)
                C[(size_t)(row + r) * N + col] = acc[fm][fn][r] * s + b;
        }
    }
}

extern "C" void kernel_launch(void* const* d_in, const int* in_sizes, int n_in,
                              void* d_out, int out_size, void* d_ws, size_t ws_size,
                              hipStream_t stream) {
    const float* x     = (const float*)d_in[0];
    const int*   qw    = (const int*)d_in[1];
    const float* scale = (const float*)d_in[2];
    const float* bias  = (const float*)d_in[3];
    float*       out   = (float*)d_out;

    const int N = in_sizes[2];            // DOUT = 4096
    const int K = in_sizes[1] / N;        // DIN  = 4096
    const int M = in_sizes[0] / K;        // B*S  = 8192

    u16* xb = (u16*)d_ws;
    u16* wb = xb + (size_t)M * K;

    cvt_x_kernel<<<2048, 256, 0, stream>>>((const float4*)x, (uint4*)xb, (M * K) / 8);
    cvt_w_kernel<<<2048, 256, 0, stream>>>((const int4*)qw, (uint4*)wb, (N * K) / 8);

    const int grid = (M / BM) * (N / BN); // 512
    gemm256<<<grid, 512, 0, stream>>>(xb, wb, scale, bias, out, M, N, K);
}

// Round 3
// 278.309 us; speedup vs baseline: 1.3468x; 1.0565x over previous
//
#include <hip/hip_runtime.h>
#include <hip/hip_bf16.h>

typedef unsigned short u16;
typedef unsigned int u32;

typedef __bf16 bf16x8 __attribute__((ext_vector_type(8)));
typedef float f32x4 __attribute__((ext_vector_type(4)));

#define AS1 __attribute__((address_space(1)))
#define AS3 __attribute__((address_space(3)))

__device__ __forceinline__ u16 f2bf(float f) {
    u32 u = __float_as_uint(f);
    u += 0x7fffu + ((u >> 16) & 1u);
    return (u16)(u >> 16);
}

__global__ void cvt_x_kernel(const float4* __restrict__ x, uint4* __restrict__ y, int n8) {
    int stride = gridDim.x * blockDim.x;
    for (int i = blockIdx.x * blockDim.x + threadIdx.x; i < n8; i += stride) {
        float4 f0 = x[2 * i + 0];
        float4 f1 = x[2 * i + 1];
        union { u16 s[8]; uint4 v; } o;
        o.s[0] = f2bf(f0.x); o.s[1] = f2bf(f0.y); o.s[2] = f2bf(f0.z); o.s[3] = f2bf(f0.w);
        o.s[4] = f2bf(f1.x); o.s[5] = f2bf(f1.y); o.s[6] = f2bf(f1.z); o.s[7] = f2bf(f1.w);
        y[i] = o.v;
    }
}

__global__ void cvt_w_kernel(const int4* __restrict__ q, uint4* __restrict__ y, int n8) {
    int stride = gridDim.x * blockDim.x;
    for (int i = blockIdx.x * blockDim.x + threadIdx.x; i < n8; i += stride) {
        int4 q0 = q[2 * i + 0];
        int4 q1 = q[2 * i + 1];
        union { u16 s[8]; uint4 v; } o;
        o.s[0] = f2bf((float)q0.x); o.s[1] = f2bf((float)q0.y);
        o.s[2] = f2bf((float)q0.z); o.s[3] = f2bf((float)q0.w);
        o.s[4] = f2bf((float)q1.x); o.s[5] = f2bf((float)q1.y);
        o.s[6] = f2bf((float)q1.z); o.s[7] = f2bf((float)q1.w);
        y[i] = o.v;
    }
}

// ===== 256x256 8-phase GEMM; full 3-bit slot swizzle (slot ^= row&7 @16B) =====
// C[m][n] = scale[n] * sum_k A[m][k]*W[n][k] + bias[n]
// BM=BN=256, BK=64, 512 thr (2Mx4N waves), LDS 128KiB dbuf, 16 MFMA/phase.

#define BM 256
#define BN 256
#define BK 64

// One phase: {ds-read subtile; stage pair; barrier; lgkm0; setprio1; 16 MFMA; setprio0; [vmcnt gate]; barrier}
// aB/bB are already KS-resolved (swizzled slot baked in); KS only indexes bfr.
template<int KS, int MLO, bool GATE, typename F>
__device__ __forceinline__ void phase(const char* aB, const char* bB,
    bf16x8 (&bfr)[2][4], f32x4 (&acc)[8][4], F&& stage)
{
    bf16x8 afr[4];
    if (MLO == 0) {
#pragma unroll
        for (int fn = 0; fn < 4; ++fn)
            bfr[KS][fn] = *(const bf16x8*)(bB + fn * 2048);
    }
#pragma unroll
    for (int fm = 0; fm < 4; ++fm)
        afr[fm] = *(const bf16x8*)(aB + (MLO + fm) * 2048);
    stage();
    __builtin_amdgcn_s_barrier();
    asm volatile("s_waitcnt lgkmcnt(0)" ::: "memory");
    __builtin_amdgcn_s_setprio(1);
#pragma unroll
    for (int fm = 0; fm < 4; ++fm)
#pragma unroll
        for (int fn = 0; fn < 4; ++fn)
            acc[MLO + fm][fn] = __builtin_amdgcn_mfma_f32_16x16x32_bf16(
                afr[fm], bfr[KS][fn], acc[MLO + fm][fn], 0, 0, 0);
    __builtin_amdgcn_s_setprio(0);
    if (GATE) asm volatile("s_waitcnt vmcnt(4)" ::: "memory");
    __builtin_amdgcn_s_barrier();
}

__global__ __launch_bounds__(512, 2) void gemm256(
    const u16* __restrict__ A,      // [M][K] bf16
    const u16* __restrict__ W,      // [N][K] bf16
    const float* __restrict__ scale,
    const float* __restrict__ bias,
    float* __restrict__ C,
    int M, int N, int K)
{
    __shared__ alignas(1024) char lds[131072];  // buf0: A@0 B@32768 ; buf1: A@65536 B@98304

    const int nwg = gridDim.x;
    int bid = blockIdx.x;
    if ((nwg & 7) == 0) { int cpx = nwg >> 3; bid = (bid & 7) * cpx + (bid >> 3); }
    const int ntn = N / BN;
    const int tm = bid / ntn, tn = bid % ntn;

    const int t = threadIdx.x;
    const int l = t & 63;
    const int w = t >> 6;
    const int wm = w >> 2, wn = w & 3;       // 2 x 4 wave grid; wave tile 128x64
    const size_t Kz = (size_t)K;

    // ---- staging: linear LDS dest (wave base + lane*16); PRE-SWIZZLED global source.
    // physical slot p = t&7 at row t>>3 holds logical slot p ^ (row&7).
    const int sRow = t >> 3;                             // 0..63 within 64-row chunk
    const int sCol = (((t & 7) ^ ((t >> 3) & 7)) * 8);   // logical element col
    const u16* aSrc = A + (size_t)(tm * BM + sRow) * Kz + sCol;
    const u16* bSrc = W + (size_t)(tn * BN + sRow) * Kz + sCol;
    const int wByte = w * 1024;

    char* dA0 = lds + wByte;
    char* dB0 = lds + 32768 + wByte;
    char* dA1 = lds + 65536 + wByte;
    char* dB1 = lds + 98304 + wByte;

    // ---- reader bases: logical slot = (l>>4) | (KS<<2); physical = logical ^ (l&7).
    // row&7 == l&7 for all fragment rows (frag offsets are multiples of 16).
    const int rowA = (wm * 128 + (l & 15)) * 128;
    const int rowB = (wn * 64  + (l & 15)) * 128;
    const int sl0 = (((l >> 4) | 0) ^ (l & 7)) * 16;   // KS=0 slot byte
    const int sl1 = (((l >> 4) | 4) ^ (l & 7)) * 16;   // KS=1 slot byte

    const char* aX0 = lds +         rowA + sl0;
    const char* aX1 = lds +         rowA + sl1;
    const char* bX0 = lds + 32768 + rowB + sl0;
    const char* bX1 = lds + 32768 + rowB + sl1;
    const char* aY0 = lds + 65536 + rowA + sl0;
    const char* aY1 = lds + 65536 + rowA + sl1;
    const char* bY0 = lds + 98304 + rowB + sl0;
    const char* bY1 = lds + 98304 + rowB + sl1;

    f32x4 acc[8][4];
#pragma unroll
    for (int i = 0; i < 8; ++i)
#pragma unroll
        for (int j = 0; j < 4; ++j) acc[i][j] = (f32x4){0.f, 0.f, 0.f, 0.f};

    const int NT = K / BK;   // 64 K-tiles

    auto stagePair = [&](const u16* src, char* dst, int kt, int c0, int c1) {
        const u16* s0 = src + (size_t)c0 * 64 * Kz + (size_t)kt * 64;
        const u16* s1 = src + (size_t)c1 * 64 * Kz + (size_t)kt * 64;
        __builtin_amdgcn_global_load_lds((const AS1 void*)s0, (AS3 void*)(dst + c0 * 8192), 16, 0, 0);
        __builtin_amdgcn_global_load_lds((const AS1 void*)s1, (AS3 void*)(dst + c1 * 8192), 16, 0, 0);
    };

    // ---- prologue: tile0 full -> buf0; tile1 B -> buf1; counted gate
    stagePair(aSrc, dA0, 0, 0, 2);
    stagePair(bSrc, dB0, 0, 0, 1);
    stagePair(bSrc, dB0, 0, 2, 3);
    stagePair(aSrc, dA0, 0, 1, 3);
    stagePair(bSrc, dB1, 1, 0, 1);
    stagePair(bSrc, dB1, 1, 2, 3);
    asm volatile("s_waitcnt vmcnt(4)" ::: "memory");
    __builtin_amdgcn_s_barrier();

    bf16x8 bfr[2][4];

    // ---- main loop: 2 K-tiles per iteration, 8 phases.
    // Stage schedule (vmcnt(4)@P4,P8 provably covers every consumed chunk):
    //  P1:(2i+1).A02->buf1  P2:(2i+1).A13->buf1  P3:e.A02->buf0  P4:e.B01->buf0 +gate
    //  P5:e.B23->buf0       P6:e.A13->buf0       P7:o.B01->buf1  P8:o.B23->buf1 +gate
#pragma unroll 1
    for (int i = 0; i < NT / 2; ++i) {
        const int yt = 2 * i + 1;
        const int e  = (2 * i + 2) & (NT - 1);   // wraps harmlessly on last iter
        const int o  = (2 * i + 3) & (NT - 1);
        phase<0, 0, false>(aX0, bX0, bfr, acc, [&] { stagePair(aSrc, dA1, yt, 0, 2); });
        phase<1, 0, false>(aX1, bX1, bfr, acc, [&] { stagePair(aSrc, dA1, yt, 1, 3); });
        phase<0, 4, false>(aX0, bX0, bfr, acc, [&] { stagePair(aSrc, dA0, e, 0, 2); });
        phase<1, 4, true >(aX1, bX1, bfr, acc, [&] { stagePair(bSrc, dB0, e, 0, 1); });
        phase<0, 0, false>(aY0, bY0, bfr, acc, [&] { stagePair(bSrc, dB0, e, 2, 3); });
        phase<1, 0, false>(aY1, bY1, bfr, acc, [&] { stagePair(aSrc, dA0, e, 1, 3); });
        phase<0, 4, false>(aY0, bY0, bfr, acc, [&] { stagePair(bSrc, dB1, o, 0, 1); });
        phase<1, 4, true >(aY1, bY1, bfr, acc, [&] { stagePair(bSrc, dB1, o, 2, 3); });
    }

    // ---- epilogue: C/D frag (16x16x32): col = lane&15, row = (lane>>4)*4 + reg
    const int colb = tn * BN + wn * 64 + (l & 15);
    const int rowb = tm * BM + wm * 128 + (l >> 4) * 4;
#pragma unroll
    for (int fn = 0; fn < 4; ++fn) {
        const int col = colb + fn * 16;
        const float s = scale[col];
        const float b = bias[col];
#pragma unroll
        for (int fm = 0; fm < 8; ++fm) {
            const int row = rowb + fm * 16;
#pragma unroll
            for (int r = 0; r < 4; ++r)
                C[(size_t)(row + r) * N + col] = acc[fm][fn][r] * s + b;
        }
    }
}

extern "C" void kernel_launch(void* const* d_in, const int* in_sizes, int n_in,
                              void* d_out, int out_size, void* d_ws, size_t ws_size,
                              hipStream_t stream) {
    const float* x     = (const float*)d_in[0];
    const int*   qw    = (const int*)d_in[1];
    const float* scale = (const float*)d_in[2];
    const float* bias  = (const float*)d_in[3];
    float*       out   = (float*)d_out;

    const int N = in_sizes[2];            // DOUT = 4096
    const int K = in_sizes[1] / N;        // DIN  = 4096
    const int M = in_sizes[0] / K;        // B*S  = 8192

    u16* xb = (u16*)d_ws;
    u16* wb = xb + (size_t)M * K;

    cvt_x_kernel<<<2048, 256, 0, stream>>>((const float4*)x, (uint4*)xb, (M * K) / 8);
    cvt_w_kernel<<<2048, 256, 0, stream>>>((const int4*)qw, (uint4*)wb, (N * K) / 8);

    const int grid = (M / BM) * (N / BN); // 512
    gemm256<<<grid, 512, 0, stream>>>(xb, wb, scale, bias, out, M, N, K);
}